// Round 9
// baseline (252.647 us; speedup 1.0000x reference)
//
#include <hip/hip_runtime.h>
#include <math.h>

// Problem constants (reference: B,F,W,H,D = 128,1024,32,64,64)
#define B_   128
#define F_   1024
#define W_   32
#define H_   64
#define K4H  256          // 4*H
#define M_   (B_ * W_)    // 4096 rows of the gate GEMM (m = b*32 + t)
#define K2_  (2 * F_)     // 2048: fp32 split into interleaved (hi,lo) bf16 pairs
#define S_   4            // K-split of the mega path
#define NIT_ 8            // 32 / S_

#define MAGIC_A 0x9E3779B1u   // barrier-1 sequence value
#define MAGIC_B 0x85EBCA77u   // barrier-2 sequence value (stale-proof vs A)

typedef __attribute__((ext_vector_type(8))) short  short8;  // 8 bf16 (MFMA A/B frag)
typedef __attribute__((ext_vector_type(4))) float  f32x4;   // MFMA C/D frag

// ---------------------------------------------------------------------------
__device__ __forceinline__ unsigned bf16_rne(float v) {
  unsigned u = __float_as_uint(v);
  return (u + 0x7FFFu + ((u >> 16) & 1u)) >> 16;
}
__device__ __forceinline__ unsigned pack_hilo(float v) {
  unsigned hi = bf16_rne(v);
  float    hf = __uint_as_float(hi << 16);
  unsigned lo = bf16_rne(v - hf);
  return hi | (lo << 16);
}
__device__ __forceinline__ float bcastlane(float v, int l) {
  return __uint_as_float(__builtin_amdgcn_readlane(__float_as_uint(v), l));
}
__device__ __forceinline__ float sigm(float v)   { return 1.f / (1.f + __expf(-v)); }
__device__ __forceinline__ float tanh_f(float v) { return 1.f - 2.f / (__expf(2.f * v) + 1.f); }

// ---------------------------------------------------------------------------
// Capture-safe grid barrier (NO cooperative launch -- R8's coop launch
// invalidated the harness's graph capture). Requires all 256 blocks
// co-resident: grid == CU count (256), LDS 36.9KB, ~170 VGPR -> >=2
// blocks/CU of capacity, so the CP schedules the whole grid at once.
// Each block publishes flags[bid]=magic (device-scope release after a
// threadfence); thread t of every block spins on flags[t]. Distinct magics
// per barrier make stale/poisoned workspace values harmless: every slot is
// written-before-awaited within this dispatch.
// ---------------------------------------------------------------------------
__device__ __forceinline__ void gridbar(unsigned* flags, int bid, int tid,
                                        unsigned magic) {
  __syncthreads();                    // block's prior work done
  __threadfence();                    // data stores visible device-wide
  if (tid == 0)
    __hip_atomic_store(&flags[bid], magic, __ATOMIC_RELEASE,
                       __HIP_MEMORY_SCOPE_AGENT);
  while (__hip_atomic_load(&flags[tid], __ATOMIC_ACQUIRE,
                           __HIP_MEMORY_SCOPE_AGENT) != magic)
    __builtin_amdgcn_s_sleep(1);
  __threadfence();
  __syncthreads();
}

// ===========================================================================
// MEGA: whole pipeline in ONE dispatch (2 grid barriers) to measure/remove
// the inter-dispatch boundary cost that R0/R4/R6/R7's invariant totals
// implicate. Phase bodies are the R0/R6 harness-verified ones, verbatim.
// ===========================================================================
__global__ __launch_bounds__(256, 1) void mega(
    const float* __restrict__ x,      // [B, F, W]
    const float* __restrict__ Wx,     // [F, 4H]
    const float* __restrict__ Wh,     // [H, 4H]
    const float* __restrict__ bl,     // [4H]
    unsigned* __restrict__ B2,        // ws: [4H][K2/2] packed
    float* __restrict__ Gp,           // ws: [S][M][4H] partials
    unsigned* __restrict__ flags,     // ws: [256] barrier slots
    float* __restrict__ out) {        // [B, W, H]
  __shared__ __align__(16) unsigned smem[9216];  // 36864 B union
  const int bid = blockIdx.x;
  const int tid = threadIdx.x;
  const int wv = tid >> 6, lane = tid & 63;
  const int wm = wv & 1, wn = wv >> 1;       // gemm wave -> 64x64 quadrant
  const int lm = lane & 15, q = lane >> 4;   // MFMA lane decomposition

  // gemm block decode: bid -> (mtile, ntile, s); 32*2*4 = 256 exactly.
  const int mtile = bid & 31, ntile = (bid >> 5) & 1, s = bid >> 6;
  const int b0 = mtile * 4;

  float4 ax[4];
  uint4  bxr[4];
  auto pre_x = [&](int iter) {               // gemm A-side global prefetch
    const int f0 = (s * NIT_ + iter) * 32;
#pragma unroll
    for (int i = 0; i < 4; ++i) {
      int l  = tid + i * 256;                // 1024 float4 = 4 b x 32 f x 8 t
      int t0 = (l & 7) * 4;
      int fl = (l >> 3) & 31;
      int blb = l >> 8;
      ax[i] = *(const float4*)&x[(((size_t)(b0 + blb)) * F_ + (f0 + fl)) * W_ + t0];
    }
  };
  auto pre_b = [&](int iter) {               // gemm B-side global prefetch
    const int f0 = (s * NIT_ + iter) * 32;
#pragma unroll
    for (int i = 0; i < 4; ++i) {
      int l   = tid + i * 256;               // 1024 uint4 = 128 n x 8
      int c16 = l & 7;
      int nl  = l >> 3;
      bxr[i] = *(const uint4*)&B2[(size_t)(ntile * 128 + nl) * (K2_ / 2) + f0 + c16 * 4];
    }
  };

  // x-prefetch for stage 0 issues BEFORE phase A (overlaps conv with HBM).
  pre_x(0);

  // ---- Phase A: Wx -> B2 pack (blocks 0..63; R0-verified conv_w body) ----
  if (bid < 64) {
    unsigned (*T)[17] = (unsigned (*)[17])smem;
    const int f0c = bid * 16;
#pragma unroll
    for (int i = 0; i < 4; ++i) {
      int l  = tid + i * 256;                // 1024 float4 = 16 f x 64 n-groups
      int n0 = (l & 63) * 4;
      int fl = l >> 6;
      float4 v = *(const float4*)&Wx[(size_t)(f0c + fl) * K4H + n0];
      T[n0 + 0][fl] = pack_hilo(v.x);
      T[n0 + 1][fl] = pack_hilo(v.y);
      T[n0 + 2][fl] = pack_hilo(v.z);
      T[n0 + 3][fl] = pack_hilo(v.w);
    }
    __syncthreads();
#pragma unroll
    for (int i = 0; i < 4; ++i) {
      int l  = tid + i * 256;                // 1024 uint4 = 256 n x 4
      int c4 = (l & 3) * 4;
      int n  = l >> 2;
      uint4 o;
      o.x = T[n][c4 + 0]; o.y = T[n][c4 + 1]; o.z = T[n][c4 + 2]; o.w = T[n][c4 + 3];
      *(uint4*)&B2[(size_t)n * (K2_ / 2) + f0c + c4] = o;
    }
  }
  gridbar(flags, bid, tid, MAGIC_A);         // B2 visible everywhere

  // ---- Phase B: gate GEMM (all 256 blocks; R0-verified gemm_mfma body) ----
  {
    unsigned* lA = smem;                     // 128*36 uints
    unsigned* lB = smem + 128 * 36;          // 128*36 uints
    f32x4 acc[4][4];
#pragma unroll
    for (int a = 0; a < 4; ++a)
#pragma unroll
      for (int bb = 0; bb < 4; ++bb) acc[a][bb] = (f32x4){0.f, 0.f, 0.f, 0.f};

    pre_b(0);
    const int jx = (tid >> 3) & 3;           // XOR bank-spread for A's writes
    for (int iter = 0; iter < NIT_; ++iter) {
      __syncthreads();                       // previous iter's frag reads done
#pragma unroll
      for (int i = 0; i < 4; ++i) {          // A: convert + transpose
        int l  = tid + i * 256;
        int t0 = (l & 7) * 4;
        int fl = (l >> 3) & 31;
        int blb = l >> 8;
        int m0 = blb * 32 + t0;
        float vals[4] = {ax[i].x, ax[i].y, ax[i].z, ax[i].w};
#pragma unroll
        for (int j = 0; j < 4; ++j) {
          int jj = j ^ jx;
          lA[(m0 + jj) * 36 + fl] = pack_hilo(vals[jj]);
        }
      }
#pragma unroll
      for (int i = 0; i < 4; ++i) {          // B: straight b128 copy
        int l   = tid + i * 256;
        int c16 = l & 7;
        int nl  = l >> 3;
        *(uint4*)&lB[nl * 36 + c16 * 4] = bxr[i];
      }
      __syncthreads();
      if (iter + 1 < NIT_) { pre_x(iter + 1); pre_b(iter + 1); }
#pragma unroll
      for (int step = 0; step < 2; ++step) { // 2 x K2=32 MFMA steps
        short8 aF[4], bF[4];
#pragma unroll
        for (int mt = 0; mt < 4; ++mt) {
          int row = wm * 64 + mt * 16 + lm;
          aF[mt] = *(const short8*)&lA[row * 36 + step * 16 + q * 4];
        }
#pragma unroll
        for (int nt = 0; nt < 4; ++nt) {
          int row = wn * 64 + nt * 16 + lm;
          bF[nt] = *(const short8*)&lB[row * 36 + step * 16 + q * 4];
        }
#pragma unroll
        for (int mt = 0; mt < 4; ++mt)
#pragma unroll
          for (int nt = 0; nt < 4; ++nt)
            acc[mt][nt] = __builtin_amdgcn_mfma_f32_16x16x32_bf16(
                aF[mt], bF[nt], acc[mt][nt], 0, 0, 0);
      }
    }
    // epilogue: C/D layout col=lane&15, row=q*4+reg  [m89-verified]
    float* Gs = Gp + (size_t)s * ((size_t)M_ * K4H);
#pragma unroll
    for (int mt = 0; mt < 4; ++mt)
#pragma unroll
      for (int nt = 0; nt < 4; ++nt)
#pragma unroll
        for (int r = 0; r < 4; ++r) {
          int m = mtile * 128 + wm * 64 + mt * 16 + q * 4 + r;
          int n = ntile * 128 + wn * 64 + nt * 16 + lm;
          Gs[(size_t)m * K4H + n] = acc[mt][nt][r];
        }
  }
  gridbar(flags, bid, tid, MAGIC_B);         // Gp visible everywhere

  // ---- Phase C: sequential LSTM (blocks 0..127; R6-verified body) ----
  if (bid < B_) {
    float* sm = (float*)smem;
    float* sG = sm;                          // 32 rows x 260 (1040B stride)
    float (*sact)[4][64] = (float (*)[4][64])(sm + 32 * 260);
    const int b = bid, w = wv, u = lane;
    const int k = w * 64 + u;                // gate column

    float wc[64];                            // Wh column k, register-resident
#pragma unroll
    for (int j = 0; j < 64; ++j) wc[j] = Wh[j * K4H + k];
    const float bk = bl[k];

    // Preload + K-split-sum: sum_s Gp[s][b*32+t][:] -> sG[t][:]; 2048 float4
    // = 32 t x 64 float4/row, coalesced, order ss=0..3 (bit-identical).
    const float4* G4 = (const float4*)Gp + (size_t)b * 32 * (K4H / 4);
    const size_t  s4 = (size_t)M_ * K4H / 4;
#pragma unroll
    for (int i = 0; i < 8; ++i) {
      int idx = tid + i * 256;               // 0..2047
      int t = idx >> 6, c = idx & 63;
      float4 v = G4[(size_t)t * (K4H / 4) + c];
#pragma unroll
      for (int ss = 1; ss < S_; ++ss) {
        float4 p = G4[(size_t)ss * s4 + (size_t)t * (K4H / 4) + c];
        v.x += p.x; v.y += p.y; v.z += p.z; v.w += p.w;
      }
      *(float4*)&sG[t * 260 + c * 4] = v;
    }
    __syncthreads();

    float h = 0.f, c = 0.f;
    float gc = sG[k];
#pragma unroll 1
    for (int t = 0; t < W_; ++t) {
      float gn = (t + 1 < W_) ? sG[(t + 1) * 260 + k] : 0.f;
      float g0 = gc + bk, g1 = 0.f, g2 = 0.f, g3 = 0.f;
#pragma unroll
      for (int j = 0; j < 64; j += 4) {      // 4 independent FMA chains
        g0 = fmaf(bcastlane(h, j),     wc[j],     g0);
        g1 = fmaf(bcastlane(h, j + 1), wc[j + 1], g1);
        g2 = fmaf(bcastlane(h, j + 2), wc[j + 2], g2);
        g3 = fmaf(bcastlane(h, j + 3), wc[j + 3], g3);
      }
      float g = (g0 + g1) + (g2 + g3);
      float act = (w == 2) ? tanh_f(g) : sigm(g);  // wave-uniform branch
      sact[t & 1][w][u] = act;
      __syncthreads();                       // the single barrier per step
      float si = sact[t & 1][0][u];
      float sf = sact[t & 1][1][u];
      float tg = sact[t & 1][2][u];
      float so = sact[t & 1][3][u];
      c = fmaf(sf, c, si * tg);              // replicated in all 4 waves
      h = so * tanh_f(c);
      if (w == 0) sG[t * 260 + u] = c;       // stash cell state in dead row
      gc = gn;
    }
    __syncthreads();
#pragma unroll
    for (int i = 0; i < 2; ++i) {            // coalesced out epilogue
      int id = tid * 2 + i;
      int t  = id >> 4, u4 = (id & 15) * 4;
      float4 o = *(const float4*)&sG[t * 260 + u4];
      *(float4*)&out[((size_t)b * W_ + t) * H_ + u4] = o;
    }
  }
}

// ===========================================================================
// Fallback kernels (R6-verified verbatim) -- small-workspace paths only.
// ===========================================================================
__global__ __launch_bounds__(256) void conv_w(const float* __restrict__ Wx,
                                              unsigned* __restrict__ B2) {
  __shared__ unsigned T[256][17];
  const int tid = threadIdx.x;
  const int f0  = blockIdx.x * 16;
#pragma unroll
  for (int i = 0; i < 4; ++i) {
    int l = tid + i * 256;
    int n0 = (l & 63) * 4;
    int fl = l >> 6;
    float4 v = *(const float4*)&Wx[(size_t)(f0 + fl) * K4H + n0];
    T[n0 + 0][fl] = pack_hilo(v.x);
    T[n0 + 1][fl] = pack_hilo(v.y);
    T[n0 + 2][fl] = pack_hilo(v.z);
    T[n0 + 3][fl] = pack_hilo(v.w);
  }
  __syncthreads();
#pragma unroll
  for (int i = 0; i < 4; ++i) {
    int l  = tid + i * 256;
    int c4 = (l & 3) * 4;
    int n  = l >> 2;
    uint4 o;
    o.x = T[n][c4 + 0]; o.y = T[n][c4 + 1]; o.z = T[n][c4 + 2]; o.w = T[n][c4 + 3];
    *(uint4*)&B2[(size_t)n * (K2_ / 2) + f0 + c4] = o;
  }
}

template <int S>
__global__ __launch_bounds__(256, 1) void gemm_mfma(
    const float* __restrict__ x, const unsigned* __restrict__ B2,
    float* __restrict__ Gp) {
  constexpr int NIT = 32 / S;
  __shared__ unsigned lA[128 * 36];
  __shared__ unsigned lB[128 * 36];
  const int tid   = threadIdx.x;
  const int mtile = blockIdx.x;
  const int ntile = blockIdx.y;
  const int s     = blockIdx.z;
  const int wv = tid >> 6, lane = tid & 63;
  const int wm = wv & 1, wn = wv >> 1;
  const int lm = lane & 15, q = lane >> 4;

  f32x4 acc[4][4];
#pragma unroll
  for (int a = 0; a < 4; ++a)
#pragma unroll
    for (int bb = 0; bb < 4; ++bb) acc[a][bb] = (f32x4){0.f, 0.f, 0.f, 0.f};

  const int b0 = mtile * 4;
  float4 ax[4];
  uint4  bxr[4];

  auto prefetch = [&](int iter) {
    const int f0 = (s * NIT + iter) * 32;
#pragma unroll
    for (int i = 0; i < 4; ++i) {
      int l  = tid + i * 256;
      int t0 = (l & 7) * 4;
      int fl = (l >> 3) & 31;
      int bl = l >> 8;
      ax[i] = *(const float4*)&x[(((size_t)(b0 + bl)) * F_ + (f0 + fl)) * W_ + t0];
    }
#pragma unroll
    for (int i = 0; i < 4; ++i) {
      int l   = tid + i * 256;
      int c16 = l & 7;
      int nl  = l >> 3;
      bxr[i] = *(const uint4*)&B2[(size_t)(ntile * 128 + nl) * (K2_ / 2) + f0 + c16 * 4];
    }
  };

  prefetch(0);
  const int jx = (tid >> 3) & 3;
  for (int iter = 0; iter < NIT; ++iter) {
    __syncthreads();
#pragma unroll
    for (int i = 0; i < 4; ++i) {
      int l  = tid + i * 256;
      int t0 = (l & 7) * 4;
      int fl = (l >> 3) & 31;
      int bl = l >> 8;
      int m0 = bl * 32 + t0;
      float vals[4] = {ax[i].x, ax[i].y, ax[i].z, ax[i].w};
#pragma unroll
      for (int j = 0; j < 4; ++j) {
        int jj = j ^ jx;
        lA[(m0 + jj) * 36 + fl] = pack_hilo(vals[jj]);
      }
    }
#pragma unroll
    for (int i = 0; i < 4; ++i) {
      int l   = tid + i * 256;
      int c16 = l & 7;
      int nl  = l >> 3;
      *(uint4*)&lB[nl * 36 + c16 * 4] = bxr[i];
    }
    __syncthreads();
    if (iter + 1 < NIT) prefetch(iter + 1);
#pragma unroll
    for (int step = 0; step < 2; ++step) {
      short8 aF[4], bF[4];
#pragma unroll
      for (int mt = 0; mt < 4; ++mt) {
        int row = wm * 64 + mt * 16 + lm;
        aF[mt] = *(const short8*)&lA[row * 36 + step * 16 + q * 4];
      }
#pragma unroll
      for (int nt = 0; nt < 4; ++nt) {
        int row = wn * 64 + nt * 16 + lm;
        bF[nt] = *(const short8*)&lB[row * 36 + step * 16 + q * 4];
      }
#pragma unroll
      for (int mt = 0; mt < 4; ++mt)
#pragma unroll
        for (int nt = 0; nt < 4; ++nt)
          acc[mt][nt] = __builtin_amdgcn_mfma_f32_16x16x32_bf16(
              aF[mt], bF[nt], acc[mt][nt], 0, 0, 0);
    }
  }
  float* Gs = Gp + (size_t)s * ((size_t)M_ * K4H);
#pragma unroll
  for (int mt = 0; mt < 4; ++mt)
#pragma unroll
    for (int nt = 0; nt < 4; ++nt)
#pragma unroll
      for (int r = 0; r < 4; ++r) {
        int m = mtile * 128 + wm * 64 + mt * 16 + q * 4 + r;
        int n = ntile * 128 + wn * 64 + nt * 16 + lm;
        Gs[(size_t)m * K4H + n] = acc[mt][nt][r];
      }
}

template <int S>
__global__ __launch_bounds__(256, 1) void lstm_seq(
    const float* __restrict__ Gp, const float* __restrict__ Wh,
    const float* __restrict__ bl, float* __restrict__ out) {
  __shared__ float sG[32 * 260];
  __shared__ float sact[2][4][64];
  const int b = blockIdx.x, tid = threadIdx.x;
  const int w = tid >> 6, u = tid & 63;
  const int k = w * 64 + u;

  float wc[64];
#pragma unroll
  for (int j = 0; j < 64; ++j) wc[j] = Wh[j * K4H + k];
  const float bk = bl[k];

  const float4* G4 = (const float4*)Gp + (size_t)b * 32 * (K4H / 4);
  const size_t  s4 = (size_t)M_ * K4H / 4;
#pragma unroll
  for (int i = 0; i < 8; ++i) {
    int idx = tid + i * 256;
    int t = idx >> 6, c = idx & 63;
    float4 v = G4[(size_t)t * (K4H / 4) + c];
#pragma unroll
    for (int ss = 1; ss < S; ++ss) {
      float4 p = G4[(size_t)ss * s4 + (size_t)t * (K4H / 4) + c];
      v.x += p.x; v.y += p.y; v.z += p.z; v.w += p.w;
    }
    *(float4*)&sG[t * 260 + c * 4] = v;
  }
  __syncthreads();

  float h = 0.f, c = 0.f;
  float gc = sG[k];
#pragma unroll 1
  for (int t = 0; t < W_; ++t) {
    float gn = (t + 1 < W_) ? sG[(t + 1) * 260 + k] : 0.f;
    float g0 = gc + bk, g1 = 0.f, g2 = 0.f, g3 = 0.f;
#pragma unroll
    for (int j = 0; j < 64; j += 4) {
      g0 = fmaf(bcastlane(h, j),     wc[j],     g0);
      g1 = fmaf(bcastlane(h, j + 1), wc[j + 1], g1);
      g2 = fmaf(bcastlane(h, j + 2), wc[j + 2], g2);
      g3 = fmaf(bcastlane(h, j + 3), wc[j + 3], g3);
    }
    float g = (g0 + g1) + (g2 + g3);
    float act = (w == 2) ? tanh_f(g) : sigm(g);
    sact[t & 1][w][u] = act;
    __syncthreads();
    float si = sact[t & 1][0][u];
    float sf = sact[t & 1][1][u];
    float tg = sact[t & 1][2][u];
    float so = sact[t & 1][3][u];
    c = fmaf(sf, c, si * tg);
    h = so * tanh_f(c);
    if (w == 0) sG[t * 260 + u] = c;
    gc = gn;
  }
  __syncthreads();
#pragma unroll
  for (int i = 0; i < 2; ++i) {
    int id = tid * 2 + i;
    int t  = id >> 4, u4 = (id & 15) * 4;
    float4 o = *(const float4*)&sG[t * 260 + u4];
    *(float4*)&out[((size_t)b * W_ + t) * H_ + u4] = o;
  }
}

// ---------------------------------------------------------------------------
extern "C" void kernel_launch(void* const* d_in, const int* in_sizes, int n_in,
                              void* d_out, int out_size, void* d_ws, size_t ws_size,
                              hipStream_t stream) {
  // 0:x 1:W_state 2:b_state 3:W_in 4:w_attn 5:b_attn 6:Wx 7:Wh 8:b_lstm
  const float* x      = (const float*)d_in[0];
  const float* Wx     = (const float*)d_in[6];
  const float* Wh     = (const float*)d_in[7];
  const float* b_lstm = (const float*)d_in[8];
  float* out = (float*)d_out;

  const size_t gbytes = (size_t)M_ * K4H * sizeof(float);  // 4 MB per partial

  if (ws_size >= 4 * gbytes + (2u << 20)) {     // mega path (S = 4 layout)
    float*    Gp    = (float*)d_ws;
    unsigned* B2    = (unsigned*)((char*)d_ws + 4 * gbytes);
    unsigned* flags = (unsigned*)((char*)d_ws + 4 * gbytes + (1u << 20));
    mega<<<dim3(256), dim3(256), 0, stream>>>(x, Wx, Wh, b_lstm, B2, Gp,
                                              flags, out);
  } else if (ws_size >= 2 * gbytes + (1u << 20)) {  // S = 2 fallback
    float*    Gp = (float*)d_ws;
    unsigned* B2 = (unsigned*)((char*)d_ws + 2 * gbytes);
    conv_w      <<<dim3(64),       dim3(256), 0, stream>>>(Wx, B2);
    gemm_mfma<2><<<dim3(32, 2, 2), dim3(256), 0, stream>>>(x, B2, Gp);
    lstm_seq<2> <<<dim3(B_),       dim3(256), 0, stream>>>(Gp, Wh, b_lstm, out);
  } else {                                      // S = 1 fallback (5 MB ws)
    float*    Gp = (float*)d_ws;
    unsigned* B2 = (unsigned*)((char*)d_ws + gbytes);
    conv_w      <<<dim3(64),       dim3(256), 0, stream>>>(Wx, B2);
    gemm_mfma<1><<<dim3(32, 2, 1), dim3(256), 0, stream>>>(x, B2, Gp);
    lstm_seq<1> <<<dim3(B_),       dim3(256), 0, stream>>>(Gp, Wh, b_lstm, out);
  }
}

// Round 10
// 128.749 us; speedup vs baseline: 1.9623x; 1.9623x over previous
//
#include <hip/hip_runtime.h>
#include <math.h>

// Problem constants (reference: B,F,W,H,D = 128,1024,32,64,64)
#define B_   128
#define F_   1024
#define W_   32
#define H_   64
#define K4H  256          // 4*H
#define M_   (B_ * W_)    // 4096 rows of the gate GEMM (m = b*32 + t)
#define K2_  (2 * F_)     // 2048: fp32 split into interleaved (hi,lo) bf16 pairs

typedef __attribute__((ext_vector_type(8))) short  short8;  // 8 bf16 (MFMA A/B frag)
typedef __attribute__((ext_vector_type(4))) float  f32x4;   // MFMA C/D frag

// ---------------------------------------------------------------------------
// fp32 -> (hi,lo) bf16 pair packed into one uint: short[0]=hi (k2 even),
// short[1]=lo (k2 odd). hi=RNE(v), lo=RNE(v-hi) -> fp32 product via plain
// bf16 MFMA over doubled K, near-exact.
// ---------------------------------------------------------------------------
__device__ __forceinline__ unsigned bf16_rne(float v) {
  unsigned u = __float_as_uint(v);
  return (u + 0x7FFFu + ((u >> 16) & 1u)) >> 16;
}
__device__ __forceinline__ unsigned pack_hilo(float v) {
  unsigned hi = bf16_rne(v);
  float    hf = __uint_as_float(hi << 16);
  unsigned lo = bf16_rne(v - hf);
  return hi | (lo << 16);
}

// ---------------------------------------------------------------------------
// Wx [F,4H] fp32 -> B2 [4H][K2/2] uints (transposed, hi/lo packed).
// (R0-verified verbatim.)
// ---------------------------------------------------------------------------
__global__ __launch_bounds__(256) void conv_w(const float* __restrict__ Wx,
                                              unsigned* __restrict__ B2) {
  __shared__ unsigned T[256][17];  // [n][f_local], +1 pad
  const int tid = threadIdx.x;
  const int f0  = blockIdx.x * 16;
#pragma unroll
  for (int i = 0; i < 4; ++i) {
    int l = tid + i * 256;          // 1024 float4 slots = 16 f x 64 n-groups
    int n0 = (l & 63) * 4;
    int fl = l >> 6;                // 0..15
    float4 v = *(const float4*)&Wx[(size_t)(f0 + fl) * K4H + n0];
    T[n0 + 0][fl] = pack_hilo(v.x);
    T[n0 + 1][fl] = pack_hilo(v.y);
    T[n0 + 2][fl] = pack_hilo(v.z);
    T[n0 + 3][fl] = pack_hilo(v.w);
  }
  __syncthreads();
#pragma unroll
  for (int i = 0; i < 4; ++i) {
    int l  = tid + i * 256;         // 1024 uint4 slots = 256 n x 4
    int c4 = (l & 3) * 4;
    int n  = l >> 2;
    uint4 o;
    o.x = T[n][c4 + 0]; o.y = T[n][c4 + 1]; o.z = T[n][c4 + 2]; o.w = T[n][c4 + 3];
    *(uint4*)&B2[(size_t)n * (K2_ / 2) + f0 + c4] = o;
  }
}

// ---------------------------------------------------------------------------
// Gate GEMM via MFMA (R0-verified verbatim). Block tile 128(M)x128(N),
// 4 waves with 64x64 wave tiles, K-split S. Grid (32, 2, S).
// ---------------------------------------------------------------------------
template <int S>
__global__ __launch_bounds__(256, 1) void gemm_mfma(
    const float* __restrict__ x,      // [B, F, W]
    const unsigned* __restrict__ B2,  // [4H][K2/2] packed
    float* __restrict__ Gp) {         // [S][M][4H] partials
  constexpr int NIT = 32 / S;         // stage iters of 32 f (64 k2) each
  __shared__ unsigned lA[128 * 36];
  __shared__ unsigned lB[128 * 36];
  const int tid   = threadIdx.x;
  const int mtile = blockIdx.x;       // 0..31 (4 batches per tile)
  const int ntile = blockIdx.y;       // 0..1  (128 gate cols)
  const int s     = blockIdx.z;       // 0..S-1
  const int wv = tid >> 6, lane = tid & 63;
  const int wm = wv & 1, wn = wv >> 1;      // wave -> 64x64 quadrant
  const int lm = lane & 15, q = lane >> 4;  // MFMA lane decomposition

  f32x4 acc[4][4];
#pragma unroll
  for (int a = 0; a < 4; ++a)
#pragma unroll
    for (int bb = 0; bb < 4; ++bb) acc[a][bb] = (f32x4){0.f, 0.f, 0.f, 0.f};

  const int b0 = mtile * 4;
  float4 ax[4];
  uint4  bxr[4];

  auto prefetch = [&](int iter) {
    const int f0 = (s * NIT + iter) * 32;
#pragma unroll
    for (int i = 0; i < 4; ++i) {
      int l  = tid + i * 256;       // 1024 float4 = 4 b x 32 f x 8 t-groups
      int t0 = (l & 7) * 4;
      int fl = (l >> 3) & 31;
      int bl = l >> 8;
      ax[i] = *(const float4*)&x[(((size_t)(b0 + bl)) * F_ + (f0 + fl)) * W_ + t0];
    }
#pragma unroll
    for (int i = 0; i < 4; ++i) {
      int l   = tid + i * 256;      // 1024 uint4 = 128 n x 8
      int c16 = l & 7;
      int nl  = l >> 3;
      bxr[i] = *(const uint4*)&B2[(size_t)(ntile * 128 + nl) * (K2_ / 2) + f0 + c16 * 4];
    }
  };

  prefetch(0);
  const int jx = (tid >> 3) & 3;     // XOR bank-spread for A's b32 writes
  for (int iter = 0; iter < NIT; ++iter) {
    __syncthreads();                 // previous iter's frag reads done
#pragma unroll
    for (int i = 0; i < 4; ++i) {    // A: convert + transpose (t -> row m)
      int l  = tid + i * 256;
      int t0 = (l & 7) * 4;
      int fl = (l >> 3) & 31;
      int bl = l >> 8;
      int m0 = bl * 32 + t0;
      float vals[4] = {ax[i].x, ax[i].y, ax[i].z, ax[i].w};
#pragma unroll
      for (int j = 0; j < 4; ++j) {
        int jj = j ^ jx;
        lA[(m0 + jj) * 36 + fl] = pack_hilo(vals[jj]);
      }
    }
#pragma unroll
    for (int i = 0; i < 4; ++i) {    // B: straight b128 copy (pre-packed)
      int l   = tid + i * 256;
      int c16 = l & 7;
      int nl  = l >> 3;
      *(uint4*)&lB[nl * 36 + c16 * 4] = bxr[i];
    }
    __syncthreads();
    if (iter + 1 < NIT) prefetch(iter + 1);  // overlap globals with MFMA
#pragma unroll
    for (int step = 0; step < 2; ++step) {   // 2 x K2=32 MFMA steps
      short8 aF[4], bF[4];
#pragma unroll
      for (int mt = 0; mt < 4; ++mt) {
        int row = wm * 64 + mt * 16 + lm;    // A[m=lane&15][k=q*8+j]
        aF[mt] = *(const short8*)&lA[row * 36 + step * 16 + q * 4];
      }
#pragma unroll
      for (int nt = 0; nt < 4; ++nt) {
        int row = wn * 64 + nt * 16 + lm;    // B[k=q*8+j][n=lane&15]
        bF[nt] = *(const short8*)&lB[row * 36 + step * 16 + q * 4];
      }
#pragma unroll
      for (int mt = 0; mt < 4; ++mt)
#pragma unroll
        for (int nt = 0; nt < 4; ++nt)
          acc[mt][nt] = __builtin_amdgcn_mfma_f32_16x16x32_bf16(
              aF[mt], bF[nt], acc[mt][nt], 0, 0, 0);
    }
  }
  // epilogue: C/D layout col=lane&15, row=q*4+reg  [m89-verified]
  float* Gs = Gp + (size_t)s * ((size_t)M_ * K4H);
#pragma unroll
  for (int mt = 0; mt < 4; ++mt)
#pragma unroll
    for (int nt = 0; nt < 4; ++nt)
#pragma unroll
      for (int r = 0; r < 4; ++r) {
        int m = mtile * 128 + wm * 64 + mt * 16 + q * 4 + r;
        int n = ntile * 128 + wn * 64 + nt * 16 + lm;
        Gs[(size_t)m * K4H + n] = acc[mt][nt][r];
      }
}

// ---------------------------------------------------------------------------
__device__ __forceinline__ float bcastlane(float v, int l) {
  return __uint_as_float(__builtin_amdgcn_readlane(__float_as_uint(v), l));
}
__device__ __forceinline__ float sigm(float v)   { return 1.f / (1.f + __expf(-v)); }
__device__ __forceinline__ float tanh_f(float v) { return 1.f - 2.f / (__expf(2.f * v) + 1.f); }

// ---------------------------------------------------------------------------
// Sequential LSTM, R10 = R0's recurrence (best measured: per-step G
// prefetch hidden under the dot, ONE barrier/step) with a single change:
// NO global store inside the loop. R0 stored c to `out` each step; the
// step's __syncthreads then force-drains vmcnt(0), exposing the store
// (~50-150cy x 32 steps). Now c is stashed in an 8KB LDS buffer and written
// once, coalesced, at the end -- the per-step barrier drains only the G
// prefetch (issued a full step earlier, already landed) and cheap LDS ops.
// ---------------------------------------------------------------------------
template <int S>
__global__ __launch_bounds__(256, 1) void lstm_seq(
    const float* __restrict__ Gp, const float* __restrict__ Wh,
    const float* __restrict__ bl, float* __restrict__ out) {
  __shared__ float sact[2][4][64];            // [t-parity][gate-wave][u]
  __shared__ float sOut[32][64];              // cell-state stash (epilogue)
  const int b = blockIdx.x, tid = threadIdx.x;
  const int w = tid >> 6, u = tid & 63;
  const int k = w * 64 + u;                   // gate column

  float wc[64];                               // Wh column k, register-resident
#pragma unroll
  for (int j = 0; j < 64; ++j) wc[j] = Wh[j * K4H + k];
  const float bk = bl[k];
  const size_t base = (size_t)b * W_ * K4H + k;
  const size_t sstr = (size_t)M_ * K4H;

  float h = 0.f, c = 0.f;
  float p = 0.f;
#pragma unroll
  for (int ss = 0; ss < S; ++ss) p += Gp[ss * sstr + base];

#pragma unroll 1
  for (int t = 0; t < W_; ++t) {
    float nx = 0.f;
    if (t + 1 < W_) {                         // prefetch next step's G
#pragma unroll
      for (int ss = 0; ss < S; ++ss)
        nx += Gp[ss * sstr + base + (size_t)(t + 1) * K4H];
    }
    float a0 = p + bk, a1 = 0.f, a2 = 0.f, a3 = 0.f;
#pragma unroll
    for (int j = 0; j < 64; j += 4) {         // 4 independent FMA chains
      a0 = fmaf(bcastlane(h, j),     wc[j],     a0);
      a1 = fmaf(bcastlane(h, j + 1), wc[j + 1], a1);
      a2 = fmaf(bcastlane(h, j + 2), wc[j + 2], a2);
      a3 = fmaf(bcastlane(h, j + 3), wc[j + 3], a3);
    }
    float g = (a0 + a1) + (a2 + a3);
    float act = (w == 2) ? tanh_f(g) : sigm(g);   // wave-uniform branch
    sact[t & 1][w][u] = act;
    __syncthreads();                          // the single barrier per step
    float si = sact[t & 1][0][u];
    float sf = sact[t & 1][1][u];
    float tg = sact[t & 1][2][u];
    float so = sact[t & 1][3][u];
    c = fmaf(sf, c, si * tg);                 // replicated in all 4 waves
    h = so * tanh_f(c);
    if (w == 0) sOut[t][u] = c;               // LDS stash, not global
    p = nx;
  }
  __syncthreads();

  // Coalesced epilogue: sOut -> out[b][t][:], 512 float4 total.
#pragma unroll
  for (int i = 0; i < 2; ++i) {
    int id = tid * 2 + i;
    int t  = id >> 4, u4 = (id & 15) * 4;
    float4 o = *(const float4*)&sOut[t][u4];
    *(float4*)&out[((size_t)b * W_ + t) * H_ + u4] = o;
  }
}

// ---------------------------------------------------------------------------
extern "C" void kernel_launch(void* const* d_in, const int* in_sizes, int n_in,
                              void* d_out, int out_size, void* d_ws, size_t ws_size,
                              hipStream_t stream) {
  // 0:x 1:W_state 2:b_state 3:W_in 4:w_attn 5:b_attn 6:Wx 7:Wh 8:b_lstm
  const float* x      = (const float*)d_in[0];
  const float* Wx     = (const float*)d_in[6];
  const float* Wh     = (const float*)d_in[7];
  const float* b_lstm = (const float*)d_in[8];
  float* out = (float*)d_out;

  const size_t gbytes = (size_t)M_ * K4H * sizeof(float);  // 4 MB per partial

  if (ws_size >= 4 * gbytes + (1u << 20)) {     // S = 4: 256 gemm blocks
    float*    Gp = (float*)d_ws;
    unsigned* B2 = (unsigned*)((char*)d_ws + 4 * gbytes);
    conv_w      <<<dim3(64),       dim3(256), 0, stream>>>(Wx, B2);
    gemm_mfma<4><<<dim3(32, 2, 4), dim3(256), 0, stream>>>(x, B2, Gp);
    lstm_seq<4> <<<dim3(B_),       dim3(256), 0, stream>>>(Gp, Wh, b_lstm, out);
  } else if (ws_size >= 2 * gbytes + (1u << 20)) {  // S = 2
    float*    Gp = (float*)d_ws;
    unsigned* B2 = (unsigned*)((char*)d_ws + 2 * gbytes);
    conv_w      <<<dim3(64),       dim3(256), 0, stream>>>(Wx, B2);
    gemm_mfma<2><<<dim3(32, 2, 2), dim3(256), 0, stream>>>(x, B2, Gp);
    lstm_seq<2> <<<dim3(B_),       dim3(256), 0, stream>>>(Gp, Wh, b_lstm, out);
  } else {                                      // S = 1 fallback (5 MB ws)
    float*    Gp = (float*)d_ws;
    unsigned* B2 = (unsigned*)((char*)d_ws + gbytes);
    conv_w      <<<dim3(64),       dim3(256), 0, stream>>>(Wx, B2);
    gemm_mfma<1><<<dim3(32, 2, 1), dim3(256), 0, stream>>>(x, B2, Gp);
    lstm_seq<1> <<<dim3(B_),       dim3(256), 0, stream>>>(Gp, Wh, b_lstm, out);
  }
}